// Round 5
// baseline (155.396 us; speedup 1.0000x reference)
//
#include <hip/hip_runtime.h>

// B=262144 x C=101 fp32 -> 3 scalars.
//
// R5: amortize per-workgroup fixed cost. Evidence: R2 (12 waves/CU) and R4
// (24 waves/CU, cheaper scan) both land at ~44us = 2048 WGs x ~21ns/WG, with
// memory only ~40% busy and avg occupancy <1 block/CU (R2: 11.4%) despite a
// 3-block LDS budget -> WG creation/retirement rate is the cap, not work.
// Fix: 683 blocks, each grid-striding over ~3 tiles (R4's tile structure
// unchanged: 512 thr, 128-row tile, quarter-split scan, 51.7KB LDS,
// 3 blocks/CU). Block lifetime 3x -> resident count reaches capacity;
// WG-creation front overlaps execution.
//
// Penalty identity (validated R4, absmax 0):
//   pen = sum_j max(e_j - e_{j+1}, 0) - e_t + e_100   (then /S)

#define NT 512
#define TR 128
#define NC 101
#define TILE_F4 3232      // 128*101/4
#define TPB 3             // tiles per block (target)
#define LAMBDA_W 1000.0

__device__ __forceinline__ void gload_lds16(const float4* g, float4* l)
{
    __builtin_amdgcn_global_load_lds(
        (const __attribute__((address_space(1))) void*)g,
        (__attribute__((address_space(3))) void*)l,
        16, 0, 0);
}

template<int LO, int HI>
__device__ __forceinline__ void scan_quarter(const float* __restrict__ xr, int t,
                                             float& S, float& W, float& Q, float& pen)
{
    float e = __expf(xr[LO]);
    S = e;
    W = (float)LO * e;
    Q = (float)(LO * LO) * e;
    pen = 0.f;
    float ep = e;
#pragma unroll
    for (int j = LO + 1; j < HI; ++j) {
        float e2 = __expf(xr[j]);
        S += e2;
        W = fmaf(e2, (float)j, W);
        Q = fmaf(e2, (float)(j * j), Q);
        pen += fmaxf(ep - e2, 0.f);
        ep = e2;
    }
    if (HI < NC) {                       // seam: d_{HI-1} = e_{HI-1} - e_HI
        float e2 = __expf(xr[HI]);
        pen += fmaxf(ep - e2, 0.f);
    } else {
        pen += ep;                       // +e_100
    }
    if (t >= LO && t < HI)               // owner quarter: -e_t
        pen -= __expf(xr[t]);
}

__global__ __launch_bounds__(NT, 6)
void ucl_row_kernel(const float* __restrict__ x,
                    const int* __restrict__ tgt,
                    float2* __restrict__ partial,
                    int ntiles)
{
    __shared__ __align__(16) float tile[TR * NC];   // 51712 B, reused for partials
    __shared__ float red[4];

    const int tid = threadIdx.x;
    const int r   = tid & (TR - 1);
    const int q   = tid >> 7;            // quarter 0..3, wave-uniform

    float conc_acc = 0.f, pens_acc = 0.f;

    for (int tile_i = blockIdx.x; tile_i < ntiles; tile_i += gridDim.x) {
        __syncthreads();                 // prev combine reads done -> safe restage

        // ---- stage tile: 3232 float4 = 6*512 + 160, direct-to-LDS ----
        {
            const float4* __restrict__ g4 =
                (const float4*)(x + (size_t)tile_i * (TR * NC));
            float4* l4 = (float4*)tile;
#pragma unroll
            for (int k = 0; k < 6; ++k)
                gload_lds16(g4 + k * NT + tid, l4 + k * NT + tid);
            if (tid < TILE_F4 - 6 * NT)  // 160-wide tail (validated R4)
                gload_lds16(g4 + 6 * NT + tid, l4 + 6 * NT + tid);
        }
        const int t = tgt[(size_t)tile_i * TR + r];
        __syncthreads();                 // vmcnt(0): tile + t resident

        // ---- quarter scan; bank (5r+j)%32 over 64 consecutive r = 2-way free
        const float* __restrict__ xr = tile + r * NC;
        float S, W, Q, pen;
        if      (q == 0) scan_quarter< 0,  26>(xr, t, S, W, Q, pen);
        else if (q == 1) scan_quarter<26,  51>(xr, t, S, W, Q, pen);
        else if (q == 2) scan_quarter<51,  76>(xr, t, S, W, Q, pen);
        else             scan_quarter<76, 101>(xr, t, S, W, Q, pen);

        __syncthreads();                 // tile reads done -> reuse as scratch
        {
            float4* p4 = (float4*)(tile + r * 20 + q * 4);
            *p4 = make_float4(S, W, Q, pen);
        }
        __syncthreads();

        if (q == 0) {                    // combine + per-row epilogue
            const float4* p4 = (const float4*)(tile + r * 20);
            float4 a = p4[0], b = p4[1], c = p4[2], d = p4[3];
            float Sf = a.x + b.x + c.x + d.x;
            float Wf = a.y + b.y + c.y + d.y;
            float Qf = a.z + b.z + c.z + d.z;
            float Pf = a.w + b.w + c.w + d.w;
            float pred = Wf / Sf;
            float var  = fmaxf(fmaf(-pred, pred, Qf / Sf), 1e-6f);
            float err  = pred - (float)t;
            conc_acc += 0.5f * __logf(var) + err * err / (2.0f * var);
            pens_acc += Pf / Sf;
        }
    }

    // ---- block reduce once (waves 2..7 contribute zeros) ----
#pragma unroll
    for (int off = 32; off > 0; off >>= 1) {
        conc_acc += __shfl_down(conc_acc, off);
        pens_acc += __shfl_down(pens_acc, off);
    }
    if (tid < 2 * TR && (tid & 63) == 0) {
        red[(tid >> 6) * 2 + 0] = conc_acc;
        red[(tid >> 6) * 2 + 1] = pens_acc;
    }
    __syncthreads();
    if (tid == 0)
        partial[blockIdx.x] = make_float2(red[0] + red[2], red[1] + red[3]);
}

__global__ __launch_bounds__(256)
void ucl_finalize(const float2* __restrict__ partial,
                  float* __restrict__ out,
                  int nblocks, double invB)
{
    const int tid = threadIdx.x;
    double c = 0.0, p = 0.0;
    for (int i = tid; i < nblocks; i += 256) {
        float2 v = partial[i];
        c += (double)v.x;
        p += (double)v.y;
    }
#pragma unroll
    for (int off = 32; off > 0; off >>= 1) {
        c += __shfl_down(c, off);
        p += __shfl_down(p, off);
    }
    __shared__ double s[8];
    if ((tid & 63) == 0) { s[(tid >> 6) * 2] = c; s[(tid >> 6) * 2 + 1] = p; }
    __syncthreads();
    if (tid == 0) {
        double C = (s[0] + s[2] + s[4] + s[6]) * invB;
        double P = (s[1] + s[3] + s[5] + s[7]) * invB * LAMBDA_W;
        out[0] = (float)(C + P);
        out[1] = (float)C;
        out[2] = (float)P;
    }
}

extern "C" void kernel_launch(void* const* d_in, const int* in_sizes, int n_in,
                              void* d_out, int out_size, void* d_ws, size_t ws_size,
                              hipStream_t stream)
{
    const float* x   = (const float*)d_in[0];
    const int*   tgt = (const int*)d_in[1];
    float* out = (float*)d_out;
    float2* partial = (float2*)d_ws;

    const int B = in_sizes[1];                    // 262144
    const int ntiles = B / TR;                    // 2048
    const int blocks = (ntiles + TPB - 1) / TPB;  // 683

    hipLaunchKernelGGL(ucl_row_kernel, dim3(blocks), dim3(NT), 0, stream,
                       x, tgt, partial, ntiles);
    hipLaunchKernelGGL(ucl_finalize, dim3(1), dim3(256), 0, stream,
                       partial, out, blocks, 1.0 / (double)B);
}

// Round 6
// 153.749 us; speedup vs baseline: 1.0107x; 1.0107x over previous
//
#include <hip/hip_runtime.h>

// B=262144 x C=101 fp32 -> 3 scalars.
//
// R6: barrier-free register streaming. R2/R4/R5 (all LDS stage->sync->scan
// variants) converge to ~44us = 2.3 TB/s effective regardless of occupancy,
// split factor, staging mechanism, or tiles-per-block -> the phase structure
// itself is the suspect. This kernel has NO LDS tiles and NO barriers:
//   wave = 4 teams x 16 lanes; team owns one row; lane s holds j = s+16k,
//   k=0..6 (7 hoisted predicated loads, ~1.6KB wave footprint -> no L1
//   thrash; each instr touches 4x64B runs -> good line utilization).
//   e_j := 0 for j>=101, so pen = sum_j max(e_j - e_{j+1}, 0) - e_t
//   (zero-pad absorbs the +e_100 term; identity validated R4/R5, absmax 0).
//   Adjacent diffs: __shfl_down(1) + team-base shuffle of e[k+1] at the
//   s=15 seam. Moments: 4 xor-shuffles (width<16 stays in-team).
// Grid-stride 1024 blocks x 256 thr, 16 iters/wave, loads across iters
// overlap freely (only accumulators are loop-carried).

#define NC 101
#define LAMBDA_W 1000.0

__global__ __launch_bounds__(256)
void ucl_stream_kernel(const float* __restrict__ x,
                       const int* __restrict__ tgt,
                       float2* __restrict__ partial,
                       int ngroups)              // B/4 row-groups
{
    const int tid  = threadIdx.x;
    const int lane = tid & 63;
    const int s    = lane & 15;                  // slot within team
    const int gwave  = blockIdx.x * 4 + (tid >> 6);
    const int nwaves = gridDim.x * 4;

    float conc = 0.f, pens = 0.f;

    for (int g = gwave; g < ngroups; g += nwaves) {
        const int row = g * 4 + (lane >> 4);     // team's row
        const float* __restrict__ xr = x + (size_t)row * NC;
        const int t = tgt[row];                  // broadcast within team

        // ---- hoisted predicated loads, j = s + 16k ----
        float e[7];
#pragma unroll
        for (int k = 0; k < 7; ++k) {
            const int j = s + 16 * k;
            e[k] = (j < NC) ? xr[j] : 0.f;
        }
        // exp; force 0 (not exp(0)=1) on padded lanes
#pragma unroll
        for (int k = 0; k < 7; ++k) {
            const int j = s + 16 * k;
            float ee = __expf(e[k]);
            e[k] = (j < NC) ? ee : 0.f;
        }

        // ---- moments ----
        float S = 0.f, W = 0.f, Q = 0.f;
#pragma unroll
        for (int k = 0; k < 7; ++k) {
            const float fj = (float)(s + 16 * k);
            S += e[k];
            W = fmaf(e[k], fj, W);
            Q = fmaf(e[k], fj * fj, Q);
        }

        // ---- penalty: d_j = e_j - e_{j+1} (e_{101..} = 0) ----
        float pen = 0.f;
#pragma unroll
        for (int k = 0; k < 7; ++k) {
            float n1 = __shfl_down(e[k], 1);                 // s<15: e_{j+1}
            float nx = (k < 6) ? __shfl(e[k + 1], lane & 48) // own team base, k+1
                               : 0.f;
            float en = (s == 15) ? nx : n1;
            float d  = e[k] - en;
            pen += fmaxf(d, 0.f);
            const int j = s + 16 * k;
            pen -= (j == t) ? e[k] : 0.f;                    // -e_t by owner
        }

        // ---- team reduce (xor folds stay within 16-lane team) ----
#pragma unroll
        for (int off = 1; off < 16; off <<= 1) {
            S   += __shfl_xor(S, off);
            W   += __shfl_xor(W, off);
            Q   += __shfl_xor(Q, off);
            pen += __shfl_xor(pen, off);
        }

        if (s == 0) {                            // one lane per row finalizes
            float pred = W / S;
            float var  = fmaxf(fmaf(-pred, pred, Q / S), 1e-6f);
            float err  = pred - (float)t;
            conc += 0.5f * __logf(var) + err * err / (2.0f * var);
            pens += pen / S;
        }
    }

    // ---- wave reduce (values at lanes 0,16,32,48) ----
    conc += __shfl_down(conc, 16);
    pens += __shfl_down(pens, 16);
    conc += __shfl_down(conc, 32);
    pens += __shfl_down(pens, 32);

    __shared__ float red[8];
    if (lane == 0) {
        red[(tid >> 6) * 2 + 0] = conc;
        red[(tid >> 6) * 2 + 1] = pens;
    }
    __syncthreads();
    if (tid == 0)
        partial[blockIdx.x] = make_float2(red[0] + red[2] + red[4] + red[6],
                                          red[1] + red[3] + red[5] + red[7]);
}

__global__ __launch_bounds__(256)
void ucl_finalize(const float2* __restrict__ partial,
                  float* __restrict__ out,
                  int nblocks, double invB)
{
    const int tid = threadIdx.x;
    double c = 0.0, p = 0.0;
    for (int i = tid; i < nblocks; i += 256) {
        float2 v = partial[i];
        c += (double)v.x;
        p += (double)v.y;
    }
#pragma unroll
    for (int off = 32; off > 0; off >>= 1) {
        c += __shfl_down(c, off);
        p += __shfl_down(p, off);
    }
    __shared__ double sm[8];
    if ((tid & 63) == 0) { sm[(tid >> 6) * 2] = c; sm[(tid >> 6) * 2 + 1] = p; }
    __syncthreads();
    if (tid == 0) {
        double C = (sm[0] + sm[2] + sm[4] + sm[6]) * invB;
        double P = (sm[1] + sm[3] + sm[5] + sm[7]) * invB * LAMBDA_W;
        out[0] = (float)(C + P);
        out[1] = (float)C;
        out[2] = (float)P;
    }
}

extern "C" void kernel_launch(void* const* d_in, const int* in_sizes, int n_in,
                              void* d_out, int out_size, void* d_ws, size_t ws_size,
                              hipStream_t stream)
{
    const float* x   = (const float*)d_in[0];
    const int*   tgt = (const int*)d_in[1];
    float* out = (float*)d_out;
    float2* partial = (float2*)d_ws;

    const int B = in_sizes[1];        // 262144
    const int ngroups = B / 4;        // 65536
    const int blocks = 1024;

    hipLaunchKernelGGL(ucl_stream_kernel, dim3(blocks), dim3(256), 0, stream,
                       x, tgt, partial, ngroups);
    hipLaunchKernelGGL(ucl_finalize, dim3(1), dim3(256), 0, stream,
                       partial, out, blocks, 1.0 / (double)B);
}